// Round 7
// baseline (1475.313 us; speedup 1.0000x reference)
//
#include <hip/hip_runtime.h>
#include <cstdint>
#include <cstddef>
#include <type_traits>

// ---------------- problem constants ----------------
#define OUT_DIM    65
#define TREE_STRIDE 66
#define N_NODE     1023
#define N_INTN     511

typedef _Float16 f16;
typedef _Float16 f16x8 __attribute__((ext_vector_type(8)));
typedef _Float16 f16x4 __attribute__((ext_vector_type(4)));
typedef float    f32x4 __attribute__((ext_vector_type(4)));

#define MFMA(a, b, c) __builtin_amdgcn_mfma_f32_16x16x32_f16((a), (b), (c), 0, 0, 0)

// H layout: [row][k] f16, row stride 512, XOR swizzle on the 16B k-segment:
//   elem(row,k) at row*512 + ((kseg ^ (row&15))<<3) + (k&7), kseg=k>>3
// ds_read_b128 (A-frag) and ds_write_b64 (storeH) land <=2-way (free, m136).

// ---------------- fused 4-layer MLP, TR=32 rows/block, 512 thr ----------------
// Wave w owns cols [w*64, w*64+64): disjoint -> weights read once per block.
// acc[2][4] = 32 AGPR; launch_bounds(512,4) caps total regs at 128/wave ->
// 2 blocks/CU (4 waves/SIMD) — round-6 fix (was 1 block/CU, latency-exposed).
// Layer-0 sources (feats + children) are LDS-staged with coalesced loads.
__global__ __launch_bounds__(512, 4) void fused_mlp(
    const float* __restrict__ feats,
    const f16* __restrict__ w0t, const float* __restrict__ b0, int Kin,
    const f16* __restrict__ w1t, const float* __restrict__ b1,
    const f16* __restrict__ w2t, const float* __restrict__ b2,
    const f16* __restrict__ wot, const float* __restrict__ bo,
    f16* __restrict__ tree,
    int lvl, int leaf)
{
  extern __shared__ f16 S[];
  f16* H  = S;              // 32*512  = 16384 f16 (32 KiB)
  f16* Xf = S + 16384;      // feats   [32][72]  (pad stride 72: bank-safe)
  f16* Xc = Xf + 32 * 72;   // children [64][66] (internal only)

  const int tid  = threadIdx.x;
  const int wave = tid >> 6;
  const int lane = tid & 63;
  const int quad = lane >> 4;
  const int l16  = lane & 15;
  const int wcb  = wave * 64;
  const long rowBase = (long)blockIdx.x * 32;

  const f32x4 z = {0.f, 0.f, 0.f, 0.f};

  // ---- stage layer-0 sources (coalesced) ----
  if (leaf) {
    const float* fsrc = feats + rowBase * 64;
    for (int i = tid; i < 2048; i += 512) {
      int r = i >> 6, c = i & 63;
      Xf[r * 72 + c] = (f16)fsrc[i];
    }
  } else {
    // lvl >= 6 here, so all 32 rows share one batch element b
    long b = rowBase >> lvl;
    long i0 = rowBase - (b << lvl);
    long node0 = (1L << lvl) - 1 + i0;
    const float* fsrc = feats + (b * N_INTN + node0) * 64;
    for (int i = tid; i < 2048; i += 512) {
      int r = i >> 6, c = i & 63;
      Xf[r * 72 + c] = (f16)fsrc[i];
    }
    // 64 child nodes are contiguous: [2*node0+1, 2*node0+64]; 64*66 f16 = 2112 dwords
    const uint32_t* cs = (const uint32_t*)(tree + (b * N_NODE + 2 * node0 + 1) * TREE_STRIDE);
    uint32_t* cd = (uint32_t*)Xc;
    for (int i = tid; i < 2112; i += 512) cd[i] = cs[i];
  }
  __syncthreads();

  // acc[mt][nt] reg r = C[row=mt*16+l16][col=wcb+nt*16+quad*4+r]  (swapped mfma)
  auto storeH = [&](f32x4 (&acc)[2][4], const float* __restrict__ bias) {
#pragma unroll
    for (int mt = 0; mt < 2; mt++) {
#pragma unroll
      for (int nt = 0; nt < 4; nt++) {
        const int c0 = wcb + nt * 16 + quad * 4;
        const float4 bv = *(const float4*)(bias + c0);
        f16x4 hv;
        float v0 = acc[mt][nt][0] + bv.x; hv[0] = (f16)(v0 > 0.f ? v0 : 0.f);
        float v1 = acc[mt][nt][1] + bv.y; hv[1] = (f16)(v1 > 0.f ? v1 : 0.f);
        float v2 = acc[mt][nt][2] + bv.z; hv[2] = (f16)(v2 > 0.f ? v2 : 0.f);
        float v3 = acc[mt][nt][3] + bv.w; hv[3] = (f16)(v3 > 0.f ? v3 : 0.f);
        const int row = mt * 16 + l16;
        *(f16x4*)&H[row * 512 + (((c0 >> 3) ^ l16) << 3) + (quad & 1) * 4] = hv;
      }
    }
  };

  // ================= layer 0 (Kin -> 512), A from LDS =================
  {
    f32x4 acc[2][4];
#pragma unroll
    for (int i = 0; i < 2; i++)
#pragma unroll
      for (int j = 0; j < 4; j++) acc[i][j] = z;

    const int nk0 = Kin >> 5;
    for (int ki = 0; ki < nk0; ki++) {
      f16x8 a[2];
      if (ki < 2) {             // feats region: vector LDS load
#pragma unroll
        for (int mt = 0; mt < 2; mt++)
          a[mt] = *(const f16x8*)&Xf[(mt * 16 + l16) * 72 + ki * 32 + quad * 8];
      } else {                  // child region: scalar LDS gather
#pragma unroll
        for (int mt = 0; mt < 2; mt++) {
          const int row = mt * 16 + l16;
#pragma unroll
          for (int j = 0; j < 8; j++) {
            int cc = ki * 32 + quad * 8 + j - 64;   // >= 0 here
            f16 v = (f16)0.f;
            if (cc < 130) {
              int rgt = cc >= 65;
              int col = cc - rgt * 65;
              v = Xc[(2 * row + rgt) * 66 + col];
            }
            a[mt][j] = v;
          }
        }
      }
      f16x8 bb[4];
#pragma unroll
      for (int nt = 0; nt < 4; nt++) {
        int col = wcb + nt * 16 + l16;
        bb[nt] = *(const f16x8*)(w0t + (long)col * Kin + ki * 32 + quad * 8);
      }
#pragma unroll
      for (int mt = 0; mt < 2; mt++)
#pragma unroll
        for (int nt = 0; nt < 4; nt++)
          acc[mt][nt] = MFMA(bb[nt], a[mt], acc[mt][nt]);
    }
    storeH(acc, b0);
    __syncthreads();
  }

  // ================= mid layers (512 -> 512) =================
  auto midLayer = [&](const f16* __restrict__ Wt, const float* __restrict__ bias) {
    f32x4 acc[2][4];
#pragma unroll
    for (int i = 0; i < 2; i++)
#pragma unroll
      for (int j = 0; j < 4; j++) acc[i][j] = z;

    f16x8 bc[4], bn[4];
    auto loadB = [&](f16x8 (&bf)[4], int ki) {
#pragma unroll
      for (int nt = 0; nt < 4; nt++) {
        int col = wcb + nt * 16 + l16;
        bf[nt] = *(const f16x8*)(Wt + (long)col * 512 + ki * 32 + quad * 8);
      }
    };
    auto loadA = [&](f16x8 (&af)[2], int ki) {
#pragma unroll
      for (int mt = 0; mt < 2; mt++) {
        int row = mt * 16 + l16;
        af[mt] = *(const f16x8*)&H[row * 512 + ((((ki * 4 + quad) ^ l16) << 3))];
      }
    };

    loadB(bc, 0);
#pragma unroll
    for (int ki = 0; ki < 16; ki += 2) {
      f16x8 a0[2];
      loadA(a0, ki);
      loadB(bn, ki + 1);
#pragma unroll
      for (int mt = 0; mt < 2; mt++)
#pragma unroll
        for (int nt = 0; nt < 4; nt++)
          acc[mt][nt] = MFMA(bc[nt], a0[mt], acc[mt][nt]);
      f16x8 a1[2];
      loadA(a1, ki + 1);
      if (ki + 2 < 16) loadB(bc, ki + 2);
#pragma unroll
      for (int mt = 0; mt < 2; mt++)
#pragma unroll
        for (int nt = 0; nt < 4; nt++)
          acc[mt][nt] = MFMA(bn[nt], a1[mt], acc[mt][nt]);
    }

    __syncthreads();          // all waves done READING H
    storeH(acc, bias);
    __syncthreads();
  };

  midLayer(w1t, b1);
  midLayer(w2t, b2);

  // ================= out layer (512 -> 65, padded 80) =================
  // 10 tasks: (rowg in {0,1}) x (nt in {0..4}); wave does task 'wave',
  // waves 0,1 also do tasks 8,9.
  auto outTask = [&](int taskId) {
    const int rowg = taskId & 1;
    const int nt   = taskId >> 1;
    const int orow = rowg * 16 + l16;
    f32x4 oacc = z;
    const int col = nt * 16 + l16;
    f16x8 obc = *(const f16x8*)(wot + (long)col * 512 + quad * 8);
#pragma unroll
    for (int ki = 0; ki < 16; ki++) {
      f16x8 a = *(const f16x8*)&H[orow * 512 + ((((ki * 4 + quad) ^ l16) << 3))];
      f16x8 obn;
      if (ki + 1 < 16)
        obn = *(const f16x8*)(wot + (long)col * 512 + (ki + 1) * 32 + quad * 8);
      oacc = MFMA(a, obc, oacc);
      obc = obn;
    }
#pragma unroll
    for (int r = 0; r < 4; r++) {
      if (col < OUT_DIM) {
        long rg = rowBase + rowg * 16 + quad * 4 + r;
        float v = oacc[r] + bo[col];
        long b = rg >> lvl;
        long i = rg - (b << lvl);
        long node = (1L << lvl) - 1 + i;
        tree[(b * N_NODE + node) * TREE_STRIDE + col] = (f16)v;
      }
    }
  };
  if (wave < 8) outTask(wave);
  if (wave < 2) outTask(wave + 8);
}

// ---------------- tail: levels 5..0, one batch element per block ----------------
__global__ __launch_bounds__(512, 1) void tail_mlp(
    const float* __restrict__ feats,
    const f16* __restrict__ w0t, const float* __restrict__ b0,
    const f16* __restrict__ w1t, const float* __restrict__ b1,
    const f16* __restrict__ w2t, const float* __restrict__ b2,
    const f16* __restrict__ wot, const float* __restrict__ bo,
    const f16* __restrict__ tree, float* __restrict__ dOut)
{
  extern __shared__ f16 S[];
  f16* H = S;                      // 32*512
  f16* childA = S + 32 * 512;      // 32*66
  f16* childB = childA + 32 * 66;

  const int b    = blockIdx.x;
  const int tid  = threadIdx.x;
  const int wave = tid >> 6;
  const int lane = tid & 63;
  const int quad = lane >> 4;
  const int l16  = lane & 15;
  const int wcb  = wave * 64;
  const f32x4 z = {0.f, 0.f, 0.f, 0.f};

  f16* prev = childA;
  f16* cur  = childB;

  auto level = [&](auto MTc, int l) {
    constexpr int MT = decltype(MTc)::value;
    const int M = 1 << l;
    const int nodeBase = M - 1;

    auto storeH = [&](f32x4 (&acc)[MT][4], const float* __restrict__ bias) {
#pragma unroll
      for (int mt = 0; mt < MT; mt++) {
#pragma unroll
        for (int nt = 0; nt < 4; nt++) {
          const int c0 = wcb + nt * 16 + quad * 4;
          const float4 bv = *(const float4*)(bias + c0);
          f16x4 hv;
          float v0 = acc[mt][nt][0] + bv.x; hv[0] = (f16)(v0 > 0.f ? v0 : 0.f);
          float v1 = acc[mt][nt][1] + bv.y; hv[1] = (f16)(v1 > 0.f ? v1 : 0.f);
          float v2 = acc[mt][nt][2] + bv.z; hv[2] = (f16)(v2 > 0.f ? v2 : 0.f);
          float v3 = acc[mt][nt][3] + bv.w; hv[3] = (f16)(v3 > 0.f ? v3 : 0.f);
          const int row = mt * 16 + l16;
          *(f16x4*)&H[row * 512 + (((c0 >> 3) ^ l16) << 3) + (quad & 1) * 4] = hv;
        }
      }
    };

    // ---- layer 0 (K=224) ----
    {
      f32x4 acc[MT][4];
#pragma unroll
      for (int i = 0; i < MT; i++)
#pragma unroll
        for (int j = 0; j < 4; j++) acc[i][j] = z;

      for (int ki = 0; ki < 7; ki++) {
        f16x8 a[MT];
#pragma unroll
        for (int mt = 0; mt < MT; mt++) {
          int row = mt * 16 + l16;
          int rr  = row < M ? row : (M - 1);
          int nn  = nodeBase + rr;
#pragma unroll
          for (int j = 0; j < 8; j++) {
            int c = ki * 32 + quad * 8 + j;
            float v = 0.f;
            if (c < 64) {
              v = feats[((long)b * N_INTN + nn) * 64 + c];
            } else if (c < 194) {
              int cc  = c - 64;
              int rgt = cc >= 65;
              int col = rgt ? cc - 65 : cc;
              if (l == 5) {
                int ch = 2 * nn + 1 + rgt;
                v = (float)tree[((long)b * N_NODE + ch) * TREE_STRIDE + col];
              } else {
                v = (float)prev[(2 * rr + rgt) * 66 + col];
              }
            }
            a[mt][j] = (f16)v;
          }
        }
        f16x8 bb[4];
#pragma unroll
        for (int nt = 0; nt < 4; nt++) {
          int col = wcb + nt * 16 + l16;
          bb[nt] = *(const f16x8*)(w0t + (long)col * 224 + ki * 32 + quad * 8);
        }
#pragma unroll
        for (int mt = 0; mt < MT; mt++)
#pragma unroll
          for (int nt = 0; nt < 4; nt++)
            acc[mt][nt] = MFMA(bb[nt], a[mt], acc[mt][nt]);
      }
      storeH(acc, b0);
      __syncthreads();
    }

    // ---- mid layers ----
    auto mid = [&](const f16* __restrict__ Wt, const float* __restrict__ bias) {
      f32x4 acc[MT][4];
#pragma unroll
      for (int i = 0; i < MT; i++)
#pragma unroll
        for (int j = 0; j < 4; j++) acc[i][j] = z;
#pragma unroll 4
      for (int ki = 0; ki < 16; ki++) {
        f16x8 a[MT];
#pragma unroll
        for (int mt = 0; mt < MT; mt++) {
          int row = mt * 16 + l16;
          a[mt] = *(const f16x8*)&H[row * 512 + ((((ki * 4 + quad) ^ l16) << 3))];
        }
        f16x8 bb[4];
#pragma unroll
        for (int nt = 0; nt < 4; nt++) {
          int col = wcb + nt * 16 + l16;
          bb[nt] = *(const f16x8*)(Wt + (long)col * 512 + ki * 32 + quad * 8);
        }
#pragma unroll
        for (int mt = 0; mt < MT; mt++)
#pragma unroll
          for (int nt = 0; nt < 4; nt++)
            acc[mt][nt] = MFMA(bb[nt], a[mt], acc[mt][nt]);
      }
      __syncthreads();
      storeH(acc, bias);
      __syncthreads();
    };
    mid(w1t, b1);
    mid(w2t, b2);

    // ---- out layer ----
    if (wave < MT) {
      f32x4 oacc[5];
#pragma unroll
      for (int i = 0; i < 5; i++) oacc[i] = z;
      const int orow = wave * 16 + l16;
#pragma unroll 4
      for (int ki = 0; ki < 16; ki++) {
        f16x8 a = *(const f16x8*)&H[orow * 512 + ((((ki * 4 + quad) ^ l16) << 3))];
        f16x8 ob[5];
#pragma unroll
        for (int nt = 0; nt < 5; nt++) {
          int col = nt * 16 + l16;
          ob[nt] = *(const f16x8*)(wot + (long)col * 512 + ki * 32 + quad * 8);
        }
#pragma unroll
        for (int nt = 0; nt < 5; nt++)
          oacc[nt] = MFMA(a, ob[nt], oacc[nt]);
      }
#pragma unroll
      for (int nt = 0; nt < 5; nt++)
#pragma unroll
        for (int r = 0; r < 4; r++) {
          int col = nt * 16 + l16;
          int row = wave * 16 + quad * 4 + r;
          if (col < OUT_DIM && row < M) {
            float v = oacc[nt][r] + bo[col];
            if (l == 0) {
              if (col == 0 && row == 0) dOut[b] = v;
            } else {
              cur[row * 66 + col] = (f16)v;
            }
          }
        }
    }
    __syncthreads();
    f16* t = prev; prev = cur; cur = t;
  };

  level(std::integral_constant<int, 2>{}, 5);
  level(std::integral_constant<int, 1>{}, 4);
  level(std::integral_constant<int, 1>{}, 3);
  level(std::integral_constant<int, 1>{}, 2);
  level(std::integral_constant<int, 1>{}, 1);
  level(std::integral_constant<int, 1>{}, 0);
}

// ---------------- merged weight transpose+cast ----------------
struct WSeg { const float* W; f16* Wt; int K, N, Kpad, start; };
struct WPack { WSeg s[8]; int total; };

__global__ void wcast_all(WPack p) {
  int idx = blockIdx.x * 256 + threadIdx.x;
  if (idx >= p.total) return;
  int si = 0;
#pragma unroll
  for (int i = 1; i < 8; i++) if (idx >= p.s[i].start) si = i;
  WSeg sg = p.s[si];
  int e = idx - sg.start;
  int n = e / sg.Kpad, k = e - n * sg.Kpad;
  float v = (n < sg.N && k < sg.K) ? sg.W[(long)k * sg.N + n] : 0.f;
  sg.Wt[e] = (f16)v;
}

// ---------------- host orchestration ----------------
extern "C" void kernel_launch(void* const* d_in, const int* in_sizes, int n_in,
                              void* d_out, int out_size, void* d_ws, size_t ws_size,
                              hipStream_t stream) {
  const float* leaf_feats     = (const float*)d_in[0];
  const float* internal_feats = (const float*)d_in[1];
  const float* lw0 = (const float*)d_in[2];
  const float* lb0 = (const float*)d_in[3];
  const float* lw1 = (const float*)d_in[4];
  const float* lb1 = (const float*)d_in[5];
  const float* lw2 = (const float*)d_in[6];
  const float* lb2 = (const float*)d_in[7];
  const float* lwo = (const float*)d_in[8];
  const float* lbo = (const float*)d_in[9];
  const float* iw0 = (const float*)d_in[10];
  const float* ib0 = (const float*)d_in[11];
  const float* iw1 = (const float*)d_in[12];
  const float* ib1 = (const float*)d_in[13];
  const float* iw2 = (const float*)d_in[14];
  const float* ib2 = (const float*)d_in[15];
  const float* iwo = (const float*)d_in[16];
  const float* ibo = (const float*)d_in[17];
  float* dOut = (float*)d_out;

  char* ws = (char*)d_ws;
  size_t off = 0;
  auto alloc = [&](size_t bytes) -> void* {
    void* p = ws + off;
    off += (bytes + 255) & ~(size_t)255;
    return p;
  };

  f16* lw0t = (f16*)alloc((size_t)512 * 64 * 2);
  f16* lw1t = (f16*)alloc((size_t)512 * 512 * 2);
  f16* lw2t = (f16*)alloc((size_t)512 * 512 * 2);
  f16* lwot = (f16*)alloc((size_t)128 * 512 * 2);
  f16* iw0t = (f16*)alloc((size_t)512 * 224 * 2);
  f16* iw1t = (f16*)alloc((size_t)512 * 512 * 2);
  f16* iw2t = (f16*)alloc((size_t)512 * 512 * 2);
  f16* iwot = (f16*)alloc((size_t)128 * 512 * 2);
  f16* tree = (f16*)alloc((size_t)256 * N_NODE * TREE_STRIDE * 2);

  WPack p;
  int cum = 0;
  auto seg = [&](int i, const float* W, f16* Wt, int K, int N, int Kpad, int Npad) {
    p.s[i] = {W, Wt, K, N, Kpad, cum};
    cum += Kpad * Npad;
  };
  seg(0, lw0, lw0t, 64, 512, 64, 512);
  seg(1, lw1, lw1t, 512, 512, 512, 512);
  seg(2, lw2, lw2t, 512, 512, 512, 512);
  seg(3, lwo, lwot, 512, 65, 512, 128);
  seg(4, iw0, iw0t, 194, 512, 224, 512);
  seg(5, iw1, iw1t, 512, 512, 512, 512);
  seg(6, iw2, iw2t, 512, 512, 512, 512);
  seg(7, iwo, iwot, 512, 65, 512, 128);
  p.total = cum;
  wcast_all<<<dim3((cum + 255) / 256), dim3(256), 0, stream>>>(p);

  static bool attrSet = false;
  if (!attrSet) {
    hipFuncSetAttribute(reinterpret_cast<const void*>(fused_mlp),
                        hipFuncAttributeMaxDynamicSharedMemorySize, 65536);
    hipFuncSetAttribute(reinterpret_cast<const void*>(tail_mlp),
                        hipFuncAttributeMaxDynamicSharedMemorySize, 65536);
    attrSet = true;
  }

  const size_t fusedShmem = (size_t)(32 * 512 + 32 * 72 + 64 * 66) * sizeof(f16); // 45824 B

  // leaf pass: 131072 rows -> nodes 511..1022
  fused_mlp<<<dim3(4096), dim3(512), fusedShmem, stream>>>(
      leaf_feats, lw0t, lb0, 64, lw1t, lb1, lw2t, lb2, lwot, lbo,
      tree, 9, 1);

  // big internal levels 8..6
  for (int l = 8; l >= 6; l--) {
    long rows = 256L << l;
    fused_mlp<<<dim3((unsigned)(rows / 32)), dim3(512), fusedShmem, stream>>>(
        internal_feats, iw0t, ib0, 224, iw1t, ib1, iw2t, ib2, iwot, ibo,
        tree, l, 0);
  }

  // levels 5..0 in one dispatch (one block per batch element)
  const size_t tailShmem = (size_t)(32 * 512 + 2 * 32 * 66) * sizeof(f16);
  tail_mlp<<<dim3(256), dim3(512), tailShmem, stream>>>(
      internal_feats, iw0t, ib0, iw1t, ib1, iw2t, ib2, iwot, ibo, tree, dOut);

  (void)in_sizes; (void)n_in; (void)out_size; (void)ws_size;
}

// Round 8
// 825.674 us; speedup vs baseline: 1.7868x; 1.7868x over previous
//
#include <hip/hip_runtime.h>
#include <cstdint>
#include <cstddef>
#include <type_traits>

// ---------------- problem constants ----------------
#define OUT_DIM    65
#define TREE_STRIDE 66
#define N_NODE     1023
#define N_INTN     511

typedef _Float16 f16;
typedef _Float16 f16x8 __attribute__((ext_vector_type(8)));
typedef _Float16 f16x4 __attribute__((ext_vector_type(4)));
typedef float    f32x4 __attribute__((ext_vector_type(4)));

#define MFMA(a, b, c) __builtin_amdgcn_mfma_f32_16x16x32_f16((a), (b), (c), 0, 0, 0)

__device__ __forceinline__ void gload_lds16(const void* g, void* l) {
  __builtin_amdgcn_global_load_lds(
      (const __attribute__((address_space(1))) void*)(uintptr_t)g,
      (__attribute__((address_space(3))) void*)(uint32_t)(uintptr_t)l, 16, 0, 0);
}

// stage one BK=32 chunk of Wt[col][K] (512 cols) into buf.
// seg s holds col=s>>2, kpart=(s^col)&3 -> 4 consecutive threads read the SAME
// 64-B global line (permuted within) = coalesced; frag read lands <=2-way banks
// (r3-verified pattern).
__device__ __forceinline__ void stageB(const f16* __restrict__ Wt, int K, int k0,
                                       f16* __restrict__ buf, int tid) {
#pragma unroll
  for (int j = 0; j < 4; j++) {
    int s = tid + j * 512;
    int col = s >> 2;
    int kp = (s ^ col) & 3;
    gload_lds16(Wt + (long)col * K + k0 + kp * 8, buf + s * 8);
  }
}

// H swizzle: elem(row,k) at row*512 + (((k>>3) ^ (row&15))<<3) + (k&7)
template<int MT>
__device__ __forceinline__ void storeH_fn(f16* __restrict__ H, f32x4 (&acc)[MT][4],
                                          const float* __restrict__ bias,
                                          int wcb, int quad, int l16) {
#pragma unroll
  for (int mt = 0; mt < MT; mt++) {
#pragma unroll
    for (int nt = 0; nt < 4; nt++) {
      const int c0 = wcb + nt * 16 + quad * 4;
      const float4 bv = *(const float4*)(bias + c0);
      f16x4 hv;
      float v0 = acc[mt][nt][0] + bv.x; hv[0] = (f16)(v0 > 0.f ? v0 : 0.f);
      float v1 = acc[mt][nt][1] + bv.y; hv[1] = (f16)(v1 > 0.f ? v1 : 0.f);
      float v2 = acc[mt][nt][2] + bv.z; hv[2] = (f16)(v2 > 0.f ? v2 : 0.f);
      float v3 = acc[mt][nt][3] + bv.w; hv[3] = (f16)(v3 > 0.f ? v3 : 0.f);
      const int row = mt * 16 + l16;
      *(f16x4*)&H[row * 512 + (((c0 >> 3) ^ l16) << 3) + (quad & 1) * 4] = hv;
    }
  }
}

// one 512-col layer with LDS-staged B (BK=32 chunks, chunk-ahead prefetch).
// DBUF=false: single-buffer B0 (2 barriers/chunk) — used when B1 holds data.
template<int MT, bool DBUF, typename GetA>
__device__ __forceinline__ void run_layer(
    const f16* __restrict__ Wt, int K, const float* __restrict__ bias,
    f16* __restrict__ H, f16* __restrict__ B0, f16* __restrict__ B1,
    int tid, int wave, int quad, int l16, GetA getA)
{
  const int wcb = wave * 64;
  const f32x4 z = {0.f, 0.f, 0.f, 0.f};
  f32x4 acc[MT][4];
#pragma unroll
  for (int i = 0; i < MT; i++)
#pragma unroll
    for (int j = 0; j < 4; j++) acc[i][j] = z;

  const int nc = K >> 5;
  if (DBUF) stageB(Wt, K, 0, B0, tid);
  for (int c = 0; c < nc; c++) {
    f16* Bc;
    if (DBUF) {
      Bc = (c & 1) ? B1 : B0;
      __syncthreads();                          // chunk c ready; chunk c-1 readers done
      if (c + 1 < nc) stageB(Wt, K, (c + 1) * 32, (c & 1) ? B0 : B1, tid);
    } else {
      Bc = B0;
      stageB(Wt, K, c * 32, B0, tid);
      __syncthreads();
    }
    f16x8 bf[4];
#pragma unroll
    for (int nt = 0; nt < 4; nt++) {
      int col = wcb + nt * 16 + l16;
      bf[nt] = *(const f16x8*)&Bc[(col << 5) + ((quad ^ (l16 & 3)) << 3)];
    }
    f16x8 af[MT];
#pragma unroll
    for (int mt = 0; mt < MT; mt++) af[mt] = getA(c, mt);
#pragma unroll
    for (int mt = 0; mt < MT; mt++)
#pragma unroll
      for (int nt = 0; nt < 4; nt++)
        acc[mt][nt] = MFMA(bf[nt], af[mt], acc[mt][nt]);   // swapped: row=l16, col=quad*4+r
    if (!DBUF) __syncthreads();                 // readers done before overwrite
  }
  __syncthreads();                              // all H/B reads of this layer done
  storeH_fn<MT>(H, acc, bias, wcb, quad, l16);
  __syncthreads();
}

// ---------------- fused 4-layer MLP, 64 rows/block, 512 thr ----------------
// LDS: H 64KB | B0 32KB | B1 32KB (B1 aliased by Xf/Xc during layer 0) = 128 KiB
__global__ __launch_bounds__(512, 2) void fused_mlp(
    const float* __restrict__ feats,
    const f16* __restrict__ w0t, const float* __restrict__ b0, int Kin,
    const f16* __restrict__ w1t, const float* __restrict__ b1,
    const f16* __restrict__ w2t, const float* __restrict__ b2,
    const f16* __restrict__ wot, const float* __restrict__ bo,
    f16* __restrict__ tree, int lvl, int leaf)
{
  extern __shared__ f16 S[];
  f16* H  = S;            // 32768 f16
  f16* B0 = S + 32768;    // 16384 f16
  f16* B1 = S + 49152;    // 16384 f16
  f16* Xf = B1;           // [64][72]  (layer-0 only, internal)
  f16* Xc = B1 + 4608;    // [128][66] (layer-0 only, internal)

  const int tid  = threadIdx.x;
  const int wave = tid >> 6;
  const int lane = tid & 63;
  const int quad = lane >> 4;
  const int l16  = lane & 15;
  const long rowBase = (long)blockIdx.x * 64;

  long bb = 0, node0 = 0;
  if (!leaf) {
    bb = rowBase >> lvl;
    node0 = (1L << lvl) - 1 + (rowBase - (bb << lvl));
    // stage feats (coalesced f32->f16) and the 128 contiguous children
    const float* fsrc = feats + (bb * N_INTN + node0) * 64;
    for (int i = tid; i < 4096; i += 512) {
      int r = i >> 6, cc = i & 63;
      Xf[r * 72 + cc] = (f16)fsrc[i];
    }
    const uint32_t* cs = (const uint32_t*)(tree + (bb * N_NODE + 2 * node0 + 1) * TREE_STRIDE);
    uint32_t* cd = (uint32_t*)Xc;
    for (int i = tid; i < 4224; i += 512) cd[i] = cs[i];
    __syncthreads();
  }

  // ---- layer 0 (single-buffered B: B1 holds Xf/Xc) ----
  if (leaf) {
    auto getA0 = [&](int c, int mt) -> f16x8 {
      const float4* p = (const float4*)(feats + (rowBase + mt * 16 + l16) * 64 + c * 32 + quad * 8);
      float4 u0 = p[0], u1 = p[1];
      f16x8 a;
      a[0] = (f16)u0.x; a[1] = (f16)u0.y; a[2] = (f16)u0.z; a[3] = (f16)u0.w;
      a[4] = (f16)u1.x; a[5] = (f16)u1.y; a[6] = (f16)u1.z; a[7] = (f16)u1.w;
      return a;
    };
    run_layer<4, false>(w0t, Kin, b0, H, B0, B1, tid, wave, quad, l16, getA0);
  } else {
    auto getA0 = [&](int c, int mt) -> f16x8 {
      int row = mt * 16 + l16;
      if (c < 2) return *(const f16x8*)&Xf[row * 72 + c * 32 + quad * 8];
      f16x8 a;
#pragma unroll
      for (int j = 0; j < 8; j++) {
        int cc = c * 32 + quad * 8 + j - 64;   // >= 0 for c >= 2
        f16 v = (f16)0.f;
        if (cc < 130) {
          int rgt = cc >= 65;
          v = Xc[(2 * row + rgt) * 66 + cc - rgt * 65];
        }
        a[j] = v;
      }
      return a;
    };
    run_layer<4, false>(w0t, Kin, b0, H, B0, B1, tid, wave, quad, l16, getA0);
  }

  // ---- mid layers (A from H) ----
  auto getAH = [&](int c, int mt) -> f16x8 {
    int row = mt * 16 + l16;
    return *(const f16x8*)&H[row * 512 + ((((c * 4 + quad) ^ l16) << 3))];
  };
  run_layer<4, true>(w1t, 512, b1, H, B0, B1, tid, wave, quad, l16, getAH);
  run_layer<4, true>(w2t, 512, b2, H, B0, B1, tid, wave, quad, l16, getAH);

  // ---- out layer (512 -> 65, padded 80), staged B, waves 0..3 compute ----
  {
    const f32x4 z = {0.f, 0.f, 0.f, 0.f};
    f32x4 oacc[5];
#pragma unroll
    for (int i = 0; i < 5; i++) oacc[i] = z;
    auto stageO = [&](int c, f16* buf) {
      if (tid < 320) {
        int s = tid, col = s >> 2, kp = (s ^ col) & 3;
        gload_lds16(wot + (long)col * 512 + c * 32 + kp * 8, buf + s * 8);
      }
    };
    stageO(0, B0);
    for (int c = 0; c < 16; c++) {
      f16* Bc = (c & 1) ? B1 : B0;
      __syncthreads();
      if (c < 15) stageO(c + 1, (c & 1) ? B0 : B1);
      if (wave < 4) {
        const int orow = wave * 16 + l16;
        f16x8 a = *(const f16x8*)&H[orow * 512 + ((((c * 4 + quad) ^ l16) << 3))];
#pragma unroll
        for (int nt = 0; nt < 5; nt++) {
          int col = nt * 16 + l16;
          f16x8 bf = *(const f16x8*)&Bc[(col << 5) + ((quad ^ (l16 & 3)) << 3)];
          oacc[nt] = MFMA(a, bf, oacc[nt]);   // normal: row=quad*4+r, col=nt*16+l16
        }
      }
    }
    if (wave < 4) {
#pragma unroll
      for (int nt = 0; nt < 5; nt++)
#pragma unroll
        for (int r = 0; r < 4; r++) {
          int col = nt * 16 + l16;
          if (col < OUT_DIM) {
            long rg = rowBase + wave * 16 + quad * 4 + r;
            float v = oacc[nt][r] + bo[col];
            long b2_ = rg >> lvl;
            long ii  = rg - (b2_ << lvl);
            long node = (1L << lvl) - 1 + ii;
            tree[(b2_ * N_NODE + node) * TREE_STRIDE + col] = (f16)v;
          }
        }
    }
  }
}

// ---------------- tail: levels 5..0, one batch element per block ----------------
__global__ __launch_bounds__(512, 2) void tail_mlp(
    const float* __restrict__ feats,
    const f16* __restrict__ w0t, const float* __restrict__ b0,
    const f16* __restrict__ w1t, const float* __restrict__ b1,
    const f16* __restrict__ w2t, const float* __restrict__ b2,
    const f16* __restrict__ wot, const float* __restrict__ bo,
    const f16* __restrict__ tree, float* __restrict__ dOut)
{
  extern __shared__ f16 S[];
  f16* H  = S;             // 16384 f16 (32 rows)
  f16* B0 = S + 16384;
  f16* B1 = S + 32768;
  f16* childA = S + 49152; // 2112 f16
  f16* childB = S + 51264; // 2112 f16

  const int b    = blockIdx.x;
  const int tid  = threadIdx.x;
  const int wave = tid >> 6;
  const int lane = tid & 63;
  const int quad = lane >> 4;
  const int l16  = lane & 15;
  const f32x4 z = {0.f, 0.f, 0.f, 0.f};

  f16* prev = childA;
  f16* cur  = childB;

  auto getAH = [&](int c, int mt) -> f16x8 {
    int row = mt * 16 + l16;
    return *(const f16x8*)&H[row * 512 + ((((c * 4 + quad) ^ l16) << 3))];
  };

  auto level = [&](auto MTc, int l) {
    constexpr int MT = decltype(MTc)::value;
    const int M = 1 << l;
    const int nodeBase = M - 1;

    // layer 0 (K=224): A gathered from feats/tree/prev
    auto getA0 = [&](int c, int mt) -> f16x8 {
      int row = mt * 16 + l16;
      int rr = row < M ? row : (M - 1);
      int nn = nodeBase + rr;
      f16x8 a;
#pragma unroll
      for (int j = 0; j < 8; j++) {
        int k = c * 32 + quad * 8 + j;
        float v = 0.f;
        if (k < 64) {
          v = feats[((long)b * N_INTN + nn) * 64 + k];
        } else if (k < 194) {
          int cc = k - 64;
          int rgt = cc >= 65;
          int col = cc - rgt * 65;
          if (l == 5) v = (float)tree[((long)b * N_NODE + 2 * nn + 1 + rgt) * TREE_STRIDE + col];
          else        v = (float)prev[(2 * rr + rgt) * 66 + col];
        }
        a[j] = (f16)v;
      }
      return a;
    };
    run_layer<MT, true>(w0t, 224, b0, H, B0, B1, tid, wave, quad, l16, getA0);
    run_layer<MT, true>(w1t, 512, b1, H, B0, B1, tid, wave, quad, l16, getAH);
    run_layer<MT, true>(w2t, 512, b2, H, B0, B1, tid, wave, quad, l16, getAH);

    // out layer, staged B
    {
      f32x4 oacc[5];
#pragma unroll
      for (int i = 0; i < 5; i++) oacc[i] = z;
      auto stageO = [&](int c, f16* buf) {
        if (tid < 320) {
          int s = tid, col = s >> 2, kp = (s ^ col) & 3;
          gload_lds16(wot + (long)col * 512 + c * 32 + kp * 8, buf + s * 8);
        }
      };
      stageO(0, B0);
      for (int c = 0; c < 16; c++) {
        f16* Bc = (c & 1) ? B1 : B0;
        __syncthreads();
        if (c < 15) stageO(c + 1, (c & 1) ? B0 : B1);
        if (wave < MT) {
          const int orow = wave * 16 + l16;
          f16x8 a = *(const f16x8*)&H[orow * 512 + ((((c * 4 + quad) ^ l16) << 3))];
#pragma unroll
          for (int nt = 0; nt < 5; nt++) {
            int col = nt * 16 + l16;
            f16x8 bf = *(const f16x8*)&Bc[(col << 5) + ((quad ^ (l16 & 3)) << 3)];
            oacc[nt] = MFMA(a, bf, oacc[nt]);
          }
        }
      }
      if (wave < MT) {
#pragma unroll
        for (int nt = 0; nt < 5; nt++)
#pragma unroll
          for (int r = 0; r < 4; r++) {
            int col = nt * 16 + l16;
            int row = wave * 16 + quad * 4 + r;
            if (col < OUT_DIM && row < M) {
              float v = oacc[nt][r] + bo[col];
              if (l == 0) {
                if (col == 0 && row == 0) dOut[b] = v;
              } else {
                cur[row * 66 + col] = (f16)v;
              }
            }
          }
      }
      __syncthreads();   // cur visible; safe to recycle H/B next level
    }
    f16* t = prev; prev = cur; cur = t;
  };

  level(std::integral_constant<int, 2>{}, 5);
  level(std::integral_constant<int, 1>{}, 4);
  level(std::integral_constant<int, 1>{}, 3);
  level(std::integral_constant<int, 1>{}, 2);
  level(std::integral_constant<int, 1>{}, 1);
  level(std::integral_constant<int, 1>{}, 0);
}

// ---------------- merged weight transpose+cast ----------------
struct WSeg { const float* W; f16* Wt; int K, N, Kpad, start; };
struct WPack { WSeg s[8]; int total; };

__global__ void wcast_all(WPack p) {
  int idx = blockIdx.x * 256 + threadIdx.x;
  if (idx >= p.total) return;
  int si = 0;
#pragma unroll
  for (int i = 1; i < 8; i++) if (idx >= p.s[i].start) si = i;
  WSeg sg = p.s[si];
  int e = idx - sg.start;
  int n = e / sg.Kpad, k = e - n * sg.Kpad;
  float v = (n < sg.N && k < sg.K) ? sg.W[(long)k * sg.N + n] : 0.f;
  sg.Wt[e] = (f16)v;
}

// ---------------- host orchestration ----------------
extern "C" void kernel_launch(void* const* d_in, const int* in_sizes, int n_in,
                              void* d_out, int out_size, void* d_ws, size_t ws_size,
                              hipStream_t stream) {
  const float* leaf_feats     = (const float*)d_in[0];
  const float* internal_feats = (const float*)d_in[1];
  const float* lw0 = (const float*)d_in[2];
  const float* lb0 = (const float*)d_in[3];
  const float* lw1 = (const float*)d_in[4];
  const float* lb1 = (const float*)d_in[5];
  const float* lw2 = (const float*)d_in[6];
  const float* lb2 = (const float*)d_in[7];
  const float* lwo = (const float*)d_in[8];
  const float* lbo = (const float*)d_in[9];
  const float* iw0 = (const float*)d_in[10];
  const float* ib0 = (const float*)d_in[11];
  const float* iw1 = (const float*)d_in[12];
  const float* ib1 = (const float*)d_in[13];
  const float* iw2 = (const float*)d_in[14];
  const float* ib2 = (const float*)d_in[15];
  const float* iwo = (const float*)d_in[16];
  const float* ibo = (const float*)d_in[17];
  float* dOut = (float*)d_out;

  char* ws = (char*)d_ws;
  size_t off = 0;
  auto alloc = [&](size_t bytes) -> void* {
    void* p = ws + off;
    off += (bytes + 255) & ~(size_t)255;
    return p;
  };

  f16* lw0t = (f16*)alloc((size_t)512 * 64 * 2);
  f16* lw1t = (f16*)alloc((size_t)512 * 512 * 2);
  f16* lw2t = (f16*)alloc((size_t)512 * 512 * 2);
  f16* lwot = (f16*)alloc((size_t)128 * 512 * 2);
  f16* iw0t = (f16*)alloc((size_t)512 * 224 * 2);
  f16* iw1t = (f16*)alloc((size_t)512 * 512 * 2);
  f16* iw2t = (f16*)alloc((size_t)512 * 512 * 2);
  f16* iwot = (f16*)alloc((size_t)128 * 512 * 2);
  f16* tree = (f16*)alloc((size_t)256 * N_NODE * TREE_STRIDE * 2);

  WPack p;
  int cum = 0;
  auto seg = [&](int i, const float* W, f16* Wt, int K, int N, int Kpad, int Npad) {
    p.s[i] = {W, Wt, K, N, Kpad, cum};
    cum += Kpad * Npad;
  };
  seg(0, lw0, lw0t, 64, 512, 64, 512);
  seg(1, lw1, lw1t, 512, 512, 512, 512);
  seg(2, lw2, lw2t, 512, 512, 512, 512);
  seg(3, lwo, lwot, 512, 65, 512, 128);
  seg(4, iw0, iw0t, 194, 512, 224, 512);
  seg(5, iw1, iw1t, 512, 512, 512, 512);
  seg(6, iw2, iw2t, 512, 512, 512, 512);
  seg(7, iwo, iwot, 512, 65, 512, 128);
  p.total = cum;
  wcast_all<<<dim3((cum + 255) / 256), dim3(256), 0, stream>>>(p);

  static bool attrSet = false;
  if (!attrSet) {
    hipFuncSetAttribute(reinterpret_cast<const void*>(fused_mlp),
                        hipFuncAttributeMaxDynamicSharedMemorySize, 131072);
    hipFuncSetAttribute(reinterpret_cast<const void*>(tail_mlp),
                        hipFuncAttributeMaxDynamicSharedMemorySize, 106752);
    attrSet = true;
  }

  const size_t fusedShmem = 131072;                         // H 64K + B0 32K + B1 32K
  const size_t tailShmem  = (size_t)(16384 + 16384 + 16384 + 2112 + 2112) * 2;

  // leaf pass: 131072 rows -> nodes 511..1022
  fused_mlp<<<dim3(2048), dim3(512), fusedShmem, stream>>>(
      leaf_feats, lw0t, lb0, 64, lw1t, lb1, lw2t, lb2, lwot, lbo, tree, 9, 1);

  // big internal levels 8..6
  for (int l = 8; l >= 6; l--) {
    long rows = 256L << l;
    fused_mlp<<<dim3((unsigned)(rows / 64)), dim3(512), fusedShmem, stream>>>(
        internal_feats, iw0t, ib0, 224, iw1t, ib1, iw2t, ib2, iwot, ibo, tree, l, 0);
  }

  // levels 5..0 in one dispatch (one block per batch element)
  tail_mlp<<<dim3(256), dim3(512), tailShmem, stream>>>(
      internal_feats, iw0t, ib0, iw1t, ib1, iw2t, ib2, iwot, ibo, tree, dOut);

  (void)in_sizes; (void)n_in; (void)out_size; (void)ws_size;
}